// Round 5
// baseline (287.027 us; speedup 1.0000x reference)
//
#include <hip/hip_runtime.h>
#include <hip/hip_bf16.h>

#define B_ 8
#define T_ 4096
#define D_ 1024
#define H_ 1024

typedef __attribute__((ext_vector_type(8))) short short8;
typedef __attribute__((ext_vector_type(4))) float floatx4;

#define GLOAD16(gptr, lptr) \
  __builtin_amdgcn_global_load_lds((const __attribute__((address_space(1))) void*)(gptr), \
                                   (__attribute__((address_space(3))) void*)(lptr), 16, 0, 0)

__device__ __forceinline__ ushort f2b(float f) {
  unsigned x = __builtin_bit_cast(unsigned, f);
  unsigned r = (x + 0x7fffu + ((x >> 16) & 1u)) >> 16;  // RNE, inputs finite
  return (ushort)r;
}

__global__ void cvt_kernel(const float* __restrict__ in, ushort* __restrict__ out, int n) {
  int idx = blockIdx.x * blockDim.x + threadIdx.x;
  int stride = gridDim.x * blockDim.x;
  for (long i = (long)idx * 8; i < n; i += (long)stride * 8) {
    const float4 f0 = *(const float4*)(in + i);
    const float4 f1 = *(const float4*)(in + i + 4);
    union { ushort u[8]; uint4 v; } r;
    r.u[0] = f2b(f0.x); r.u[1] = f2b(f0.y); r.u[2] = f2b(f0.z); r.u[3] = f2b(f0.w);
    r.u[4] = f2b(f1.x); r.u[5] = f2b(f1.y); r.u[6] = f2b(f1.z); r.u[7] = f2b(f1.w);
    *(uint4*)(out + i) = r.v;
  }
}

// K1: fused K/V GEMM + batch reduction. Block 256t x 64h, 8 waves (4t x 2h),
// wave tile 64t x 32h (m4 n2). Triple-buffered LDS (144 KiB), K-step = 64
// split into TWO sub-phases (m201 8-phase shape):
//   {8 ds_read k-sub s || 3 gload -> barrier -> lgkmcnt(0) -> 16 MFMA -> barrier}
// Counted vmcnt(6) once per K-step (stage p+2 in flight, p+1 drained).
// Swizzle (both sides): 16B chunk' = chunk ^ (row&7); reads 2-way (free).
__global__ __launch_bounds__(512, 2) void kv_kernel(
    const ushort* __restrict__ xb, const ushort* __restrict__ Wkb,
    const ushort* __restrict__ Wvb, const float* __restrict__ bk,
    const float* __restrict__ bv, const float* __restrict__ wbias,
    float* __restrict__ weighted) {
  extern __shared__ ushort lds[];
  ushort* const AsB = lds;              // 3 bufs x 256x64 = 3x16384 elems
  ushort* const KsB = lds + 49152;      // 3 bufs x 64x64  = 3x4096
  ushort* const VsB = lds + 61440;      // 3 bufs x 64x64  = 3x4096

  const int tid = threadIdx.x;
  const int lane = tid & 63;
  const int w = tid >> 6;       // 0..7
  const int wrow = w >> 1;      // 0..3  (64-row granule)
  const int wcol = w & 1;       // 0..1  (32-col granule)
  const int t0 = blockIdx.x * 256;
  const int h0 = blockIdx.y * 64;

  const int srow = tid >> 3;                     // 0..63
  const int swz = (tid & 7) ^ ((tid >> 3) & 7);  // source chunk (const/thread)

  const int arow = wrow * 64 + (lane & 15);
  const int bcol = wcol * 32 + (lane & 15);
  const int cs0 = (lane >> 4) ^ (lane & 7);        // k-sub 0 phys chunk
  const int cs1 = ((lane >> 4) + 4) ^ (lane & 7);  // k-sub 1

  float wbc[2], bkc[2], bvc[2];
#pragma unroll
  for (int n = 0; n < 2; ++n) {
    int h = h0 + wcol * 32 + n * 16 + (lane & 15);
    wbc[n] = wbias[h];
    bkc[n] = bk[h];
    bvc[n] = bv[h];
  }

  const ushort* xsb = xb + (size_t)(t0 + srow) * D_ + swz * 8;
  const ushort* ksb = Wkb + (size_t)(h0 + srow) * D_ + swz * 8;
  const ushort* vsb = Wvb + (size_t)(h0 + srow) * D_ + swz * 8;

  auto stage_half = [&](int p, int nb, int half) {  // 3 loads/thread
    const int b = p >> 4;
    const int kt = (p & 15) << 6;
    const ushort* xs = xsb + (size_t)b * (T_ * D_) + kt;
    ushort* Ab = AsB + nb * 16384;
    if (half == 0) {
      GLOAD16(xs, Ab + tid * 8);
      GLOAD16(xs + (size_t)64 * D_, Ab + (512 + tid) * 8);
      GLOAD16(ksb + kt, KsB + nb * 4096 + tid * 8);
    } else {
      GLOAD16(xs + (size_t)128 * D_, Ab + (1024 + tid) * 8);
      GLOAD16(xs + (size_t)192 * D_, Ab + (1536 + tid) * 8);
      GLOAD16(vsb + kt, VsB + nb * 4096 + tid * 8);
    }
  };

  floatx4 accK[4][2] = {};
  floatx4 accV[4][2] = {};
  floatx4 sumN[4][2] = {};
  floatx4 sumWV[4][2] = {};

  stage_half(0, 0, 0); stage_half(0, 0, 1);
  stage_half(1, 1, 0); stage_half(1, 1, 1);
  asm volatile("s_waitcnt vmcnt(6)" ::: "memory");  // stage(0) landed
  __builtin_amdgcn_s_barrier();

  int cur = 0, stg = 2;
  for (int p = 0; p < 128; ++p) {
    const ushort* Ac = AsB + cur * 16384;
    const ushort* Kc = KsB + cur * 4096;
    const ushort* Vc = VsB + cur * 4096;

    // ---------- phase A: k-sub 0 ----------
    {
      short8 a[4], kb2[2], vb2[2];
#pragma unroll
      for (int m = 0; m < 4; ++m)
        a[m] = *(const short8*)&Ac[(arow + m * 16) * 64 + cs0 * 8];
#pragma unroll
      for (int n = 0; n < 2; ++n) {
        kb2[n] = *(const short8*)&Kc[(bcol + n * 16) * 64 + cs0 * 8];
        vb2[n] = *(const short8*)&Vc[(bcol + n * 16) * 64 + cs0 * 8];
      }
      if (p < 126) stage_half(p + 2, stg, 0);
      __builtin_amdgcn_s_barrier();
      asm volatile("s_waitcnt lgkmcnt(0)" ::: "memory");
      __builtin_amdgcn_sched_barrier(0);
      __builtin_amdgcn_s_setprio(1);
#pragma unroll
      for (int m = 0; m < 4; ++m)
#pragma unroll
        for (int n = 0; n < 2; ++n) {
          accK[m][n] = __builtin_amdgcn_mfma_f32_16x16x32_bf16(a[m], kb2[n], accK[m][n], 0, 0, 0);
          accV[m][n] = __builtin_amdgcn_mfma_f32_16x16x32_bf16(a[m], vb2[n], accV[m][n], 0, 0, 0);
        }
      __builtin_amdgcn_s_setprio(0);
      __builtin_amdgcn_s_barrier();
    }

    // ---------- phase B: k-sub 1 ----------
    {
      short8 a[4], kb2[2], vb2[2];
#pragma unroll
      for (int m = 0; m < 4; ++m)
        a[m] = *(const short8*)&Ac[(arow + m * 16) * 64 + cs1 * 8];
#pragma unroll
      for (int n = 0; n < 2; ++n) {
        kb2[n] = *(const short8*)&Kc[(bcol + n * 16) * 64 + cs1 * 8];
        vb2[n] = *(const short8*)&Vc[(bcol + n * 16) * 64 + cs1 * 8];
      }
      if (p < 126) stage_half(p + 2, stg, 1);
      __builtin_amdgcn_s_barrier();
      asm volatile("s_waitcnt lgkmcnt(0)" ::: "memory");
      __builtin_amdgcn_sched_barrier(0);
      __builtin_amdgcn_s_setprio(1);
#pragma unroll
      for (int m = 0; m < 4; ++m)
#pragma unroll
        for (int n = 0; n < 2; ++n) {
          accK[m][n] = __builtin_amdgcn_mfma_f32_16x16x32_bf16(a[m], kb2[n], accK[m][n], 0, 0, 0);
          accV[m][n] = __builtin_amdgcn_mfma_f32_16x16x32_bf16(a[m], vb2[n], accV[m][n], 0, 0, 0);
        }
      __builtin_amdgcn_s_setprio(0);
    }

    if ((p & 15) == 15) {  // end of batch: fold into exp-weighted sums (reg-only)
#pragma unroll
      for (int m = 0; m < 4; ++m)
#pragma unroll
        for (int n = 0; n < 2; ++n) {
#pragma unroll
          for (int r = 0; r < 4; ++r) {
            float nmr = __expf(accK[m][n][r] + bkc[n] + wbc[n]);
            sumN[m][n][r] += nmr;
            sumWV[m][n][r] += nmr * (accV[m][n][r] + bvc[n]);
          }
          accK[m][n] = floatx4{0.f, 0.f, 0.f, 0.f};
          accV[m][n] = floatx4{0.f, 0.f, 0.f, 0.f};
        }
    }

    if (p < 126) { asm volatile("s_waitcnt vmcnt(6)" ::: "memory"); }
    else         { asm volatile("s_waitcnt vmcnt(0)" ::: "memory"); }
    __builtin_amdgcn_s_barrier();
    cur = (cur == 2) ? 0 : cur + 1;
    stg = (stg == 2) ? 0 : stg + 1;
  }

  // C/D layout: col = lane&15, row = (lane>>4)*4 + r
#pragma unroll
  for (int m = 0; m < 4; ++m)
#pragma unroll
    for (int n = 0; n < 2; ++n)
#pragma unroll
      for (int r = 0; r < 4; ++r) {
        int t = t0 + wrow * 64 + m * 16 + (lane >> 4) * 4 + r;
        int h = h0 + wcol * 32 + n * 16 + (lane & 15);
        weighted[(size_t)t * H_ + h] = sumWV[m][n][r] / sumN[m][n][r];
      }
}

// K2: Q GEMM + sigmoid(Q)*weighted epilogue. Block 256r x 128h, 8 waves
// (4r x 2h), wave 64x64 (m4 n4). BK=64, two sub-phases per step, triple
// buffer (144 KiB), counted vmcnt(6). Same swizzle as kv.
__global__ __launch_bounds__(512, 2) void q_kernel(
    const ushort* __restrict__ xb, const ushort* __restrict__ Wqb,
    const float* __restrict__ bq, const float* __restrict__ weighted,
    float* __restrict__ out) {
  extern __shared__ ushort lds[];
  ushort* const AsB = lds;              // 3 bufs x 256x64 = 3x16384 elems
  ushort* const BsB = lds + 49152;      // 3 bufs x 128x64 = 3x8192

  const int tid = threadIdx.x;
  const int lane = tid & 63;
  const int w = tid >> 6;     // 0..7
  const int wrow = w >> 1;    // 0..3
  const int wcol = w & 1;     // 0..1
  const int R0 = blockIdx.x * 256;  // rows over B*T (T%256==0)
  const int h0 = blockIdx.y * 128;

  const int srow = tid >> 3;                     // 0..63
  const int swz = (tid & 7) ^ ((tid >> 3) & 7);

  const int arow = wrow * 64 + (lane & 15);
  const int brow = wcol * 64 + (lane & 15);
  const int cs0 = (lane >> 4) ^ (lane & 7);
  const int cs1 = ((lane >> 4) + 4) ^ (lane & 7);

  const ushort* xsrc = xb + (size_t)(R0 + srow) * D_ + swz * 8;
  const ushort* wsrc = Wqb + (size_t)(h0 + srow) * D_ + swz * 8;

  auto stage_half = [&](int kt, int nb, int half) {  // 3 loads/thread
    ushort* Ab = AsB + nb * 16384;
    ushort* Bb = BsB + nb * 8192;
    if (half == 0) {
      GLOAD16(xsrc + kt, Ab + tid * 8);
      GLOAD16(xsrc + kt + (size_t)64 * D_, Ab + (512 + tid) * 8);
      GLOAD16(wsrc + kt, Bb + tid * 8);
    } else {
      GLOAD16(xsrc + kt + (size_t)128 * D_, Ab + (1024 + tid) * 8);
      GLOAD16(xsrc + kt + (size_t)192 * D_, Ab + (1536 + tid) * 8);
      GLOAD16(wsrc + kt + (size_t)64 * D_, Bb + (512 + tid) * 8);
    }
  };

  floatx4 acc[4][4] = {};

  stage_half(0, 0, 0); stage_half(0, 0, 1);
  stage_half(64, 1, 0); stage_half(64, 1, 1);
  asm volatile("s_waitcnt vmcnt(6)" ::: "memory");
  __builtin_amdgcn_s_barrier();

  int cur = 0, stg = 2;
  for (int it = 0; it < 16; ++it) {
    const ushort* Ac = AsB + cur * 16384;
    const ushort* Bc = BsB + cur * 8192;

    // ---------- phase A ----------
    {
      short8 a[4], bb[4];
#pragma unroll
      for (int m = 0; m < 4; ++m)
        a[m] = *(const short8*)&Ac[(arow + m * 16) * 64 + cs0 * 8];
#pragma unroll
      for (int n = 0; n < 4; ++n)
        bb[n] = *(const short8*)&Bc[(brow + n * 16) * 64 + cs0 * 8];
      if (it < 14) stage_half((it + 2) * 64, stg, 0);
      __builtin_amdgcn_s_barrier();
      asm volatile("s_waitcnt lgkmcnt(0)" ::: "memory");
      __builtin_amdgcn_sched_barrier(0);
      __builtin_amdgcn_s_setprio(1);
#pragma unroll
      for (int m = 0; m < 4; ++m)
#pragma unroll
        for (int n = 0; n < 4; ++n)
          acc[m][n] = __builtin_amdgcn_mfma_f32_16x16x32_bf16(a[m], bb[n], acc[m][n], 0, 0, 0);
      __builtin_amdgcn_s_setprio(0);
      __builtin_amdgcn_s_barrier();
    }

    // ---------- phase B ----------
    {
      short8 a[4], bb[4];
#pragma unroll
      for (int m = 0; m < 4; ++m)
        a[m] = *(const short8*)&Ac[(arow + m * 16) * 64 + cs1 * 8];
#pragma unroll
      for (int n = 0; n < 4; ++n)
        bb[n] = *(const short8*)&Bc[(brow + n * 16) * 64 + cs1 * 8];
      if (it < 14) stage_half((it + 2) * 64, stg, 1);
      __builtin_amdgcn_s_barrier();
      asm volatile("s_waitcnt lgkmcnt(0)" ::: "memory");
      __builtin_amdgcn_sched_barrier(0);
      __builtin_amdgcn_s_setprio(1);
#pragma unroll
      for (int m = 0; m < 4; ++m)
#pragma unroll
        for (int n = 0; n < 4; ++n)
          acc[m][n] = __builtin_amdgcn_mfma_f32_16x16x32_bf16(a[m], bb[n], acc[m][n], 0, 0, 0);
      __builtin_amdgcn_s_setprio(0);
    }

    if (it < 14) { asm volatile("s_waitcnt vmcnt(6)" ::: "memory"); }
    else         { asm volatile("s_waitcnt vmcnt(0)" ::: "memory"); }
    __builtin_amdgcn_s_barrier();
    cur = (cur == 2) ? 0 : cur + 1;
    stg = (stg == 2) ? 0 : stg + 1;
  }

  float bqc[4];
#pragma unroll
  for (int n = 0; n < 4; ++n)
    bqc[n] = bq[h0 + wcol * 64 + n * 16 + (lane & 15)];

#pragma unroll
  for (int m = 0; m < 4; ++m)
#pragma unroll
    for (int n = 0; n < 4; ++n)
#pragma unroll
      for (int r = 0; r < 4; ++r) {
        int row = R0 + wrow * 64 + m * 16 + (lane >> 4) * 4 + r;
        int t = row & (T_ - 1);
        int h = h0 + wcol * 64 + n * 16 + (lane & 15);
        float q = acc[m][n][r] + bqc[n];
        float sig = 1.f / (1.f + __expf(-q));
        out[(size_t)row * H_ + h] = sig * weighted[(size_t)t * H_ + h];
      }
}

extern "C" void kernel_launch(void* const* d_in, const int* in_sizes, int n_in,
                              void* d_out, int out_size, void* d_ws, size_t ws_size,
                              hipStream_t stream) {
  (void)in_sizes; (void)n_in; (void)out_size; (void)ws_size;
  const float* x = (const float*)d_in[0];
  const float* Wq = (const float*)d_in[1];
  const float* bq = (const float*)d_in[2];
  const float* Wk = (const float*)d_in[3];
  const float* bk = (const float*)d_in[4];
  const float* Wv = (const float*)d_in[5];
  const float* bv = (const float*)d_in[6];
  const float* wbias = (const float*)d_in[7];
  float* out = (float*)d_out;

  char* ws = (char*)d_ws;
  const size_t XN = (size_t)B_ * T_ * D_;   // 33,554,432
  const size_t WN = (size_t)H_ * D_;        // 1,048,576
  ushort* xb  = (ushort*)ws;                         // 64 MiB
  ushort* Wqb = (ushort*)(ws + XN * 2);              // 2 MiB
  ushort* Wkb = Wqb + WN;                            // 2 MiB
  ushort* Wvb = Wkb + WN;                            // 2 MiB
  float* weighted = (float*)(ws + XN * 2 + 3 * WN * 2);  // 16 MiB

  (void)hipFuncSetAttribute((const void*)kv_kernel,
                            hipFuncAttributeMaxDynamicSharedMemorySize, 147456);
  (void)hipFuncSetAttribute((const void*)q_kernel,
                            hipFuncAttributeMaxDynamicSharedMemorySize, 147456);

  cvt_kernel<<<2048, 256, 0, stream>>>(x, xb, (int)XN);
  cvt_kernel<<<512, 256, 0, stream>>>(Wq, Wqb, (int)WN);
  cvt_kernel<<<512, 256, 0, stream>>>(Wk, Wkb, (int)WN);
  cvt_kernel<<<512, 256, 0, stream>>>(Wv, Wvb, (int)WN);

  kv_kernel<<<dim3(T_ / 256, H_ / 64), 512, 147456, stream>>>(xb, Wkb, Wvb, bk, bv, wbias, weighted);
  q_kernel<<<dim3((B_ * T_) / 256, H_ / 128), 512, 147456, stream>>>(xb, Wqb, bq, weighted, out);
}